// Round 3
// baseline (138.486 us; speedup 1.0000x reference)
//
#include <hip/hip_runtime.h>
#include <hip/hip_bf16.h>

#define NN 8192
#define BB 4096
#define DD 256
#define TILE 128
#define NT (NN / TILE)              // 64
#define NBLK (NT * (NT + 1) / 2)    // 2080 triangular tiles
#define KSCALE 2.8853900817779268f  // 2 * log2(e): exp(sim) = exp2(KSCALE * dot)

typedef __attribute__((ext_vector_type(8))) short short8;
typedef __attribute__((ext_vector_type(4))) float f32x4;

#if defined(__has_builtin)
#if __has_builtin(__builtin_amdgcn_exp2f)
#define EXP2F(x) __builtin_amdgcn_exp2f(x)
#endif
#endif
#ifndef EXP2F
static __device__ __forceinline__ float exp2_asm(float x) {
    float r; asm("v_exp_f32 %0, %1" : "=v"(r) : "v"(x)); return r;
}
#define EXP2F(x) exp2_asm(x)
#endif

static __device__ __forceinline__ ushort f2bf(float x) {
    __hip_bfloat16 h = __float2bfloat16(x);
    return *reinterpret_cast<ushort*>(&h);
}
static __device__ __forceinline__ float bf2f(short u) {
    unsigned int x = (unsigned int)(ushort)u << 16;
    float f; __builtin_memcpy(&f, &x, 4); return f;
}

// Kernel 1: L2-normalize rows of concat(z_i,z_j) -> zn (bf16) and zns = KSCALE*zn (bf16)
__global__ __launch_bounds__(256) void norm_kernel(const float* __restrict__ zi,
                                                   const float* __restrict__ zj,
                                                   ushort* __restrict__ zn,
                                                   ushort* __restrict__ zns) {
    int row  = (blockIdx.x * 256 + threadIdx.x) >> 6;
    int lane = threadIdx.x & 63;
    const float* src = (row < BB) ? (zi + (size_t)row * DD)
                                  : (zj + (size_t)(row - BB) * DD);
    float4 v = ((const float4*)src)[lane];
    float ss = v.x * v.x + v.y * v.y + v.z * v.z + v.w * v.w;
    #pragma unroll
    for (int m = 32; m; m >>= 1) ss += __shfl_xor(ss, m, 64);
    float inv = 1.0f / fmaxf(sqrtf(ss), 1e-8f);
    ushort4 o, os;
    o.x  = f2bf(v.x * inv);            o.y  = f2bf(v.y * inv);
    o.z  = f2bf(v.z * inv);            o.w  = f2bf(v.w * inv);
    float invs = inv * KSCALE;
    os.x = f2bf(v.x * invs);           os.y = f2bf(v.y * invs);
    os.z = f2bf(v.z * invs);           os.w = f2bf(v.w * invs);
    ((ushort4*)(zn  + (size_t)row * DD))[lane] = o;
    ((ushort4*)(zns + (size_t)row * DD))[lane] = os;
}

// Kernel 2: triangular-tile exp-sum. Tile (bi,bj), bi<=bj, 128x128.
// Each exp(sim) accumulates into psum[row]; for off-diag tiles also psum[col].
// 4 waves x 32 rows; A (scaled rows) in registers; B (cols = zn rows) staged
// via global_load_lds into double-buffered swizzled LDS.
__global__ __launch_bounds__(256, 4) void sim_kernel(const ushort* __restrict__ zn,
                                                     const ushort* __restrict__ zns,
                                                     float* __restrict__ psum) {
    __shared__ int4  lds4[2][1024];   // 2 bufs x (32 rows x 32 granules of 16B) = 32 KB
    __shared__ float csum[TILE];

    const int tid  = threadIdx.x;
    const int w    = tid >> 6;
    const int lane = tid & 63;
    const int l15  = lane & 15;
    const int lhi  = lane >> 4;

    // decode triangular pair: idx = bj*(bj+1)/2 + bi, bi <= bj
    int idx = blockIdx.x;
    int bj  = (int)((sqrtf(8.0f * (float)idx + 1.0f) - 1.0f) * 0.5f);
    while ((bj + 1) * (bj + 2) / 2 <= idx) ++bj;
    while (bj * (bj + 1) / 2 > idx) --bj;
    int bi = idx - bj * (bj + 1) / 2;

    const int  rowbase = bi * TILE + w * 32;
    const int  colbase = bj * TILE;
    const bool offdiag = (bi != bj);

    if (tid < TILE) csum[tid] = 0.f;

    // A fragments: 2 x 16-row subtiles x 8 k-steps (scaled rows) = 64 VGPR
    short8 a0[8], a1[8];
    #pragma unroll
    for (int kk = 0; kk < 8; ++kk) {
        a0[kk] = *(const short8*)(zns + (size_t)(rowbase + l15)      * DD + kk * 32 + lhi * 8);
        a1[kk] = *(const short8*)(zns + (size_t)(rowbase + 16 + l15) * DD + kk * 32 + lhi * 8);
    }

    f32x4 sume0 = {0.f, 0.f, 0.f, 0.f}, sume1 = {0.f, 0.f, 0.f, 0.f};

    // stage 32 cols (zn rows) x 256 K into buf; linear LDS dest, inverse-swizzled src.
    auto STAGE = [&](int buf, int ct) {
        const ushort* base = zn + (size_t)(colbase + ct * 32) * DD;
        #pragma unroll
        for (int i = 0; i < 4; ++i) {
            int d = w * 256 + i * 64 + lane;       // dest granule (16B units)
            int r = d >> 5, c = d & 31;
            const ushort* src = base + (size_t)r * DD + (size_t)((c ^ (r & 7)) * 8);
            __builtin_amdgcn_global_load_lds(
                (__attribute__((address_space(1))) void*)src,
                (__attribute__((address_space(3))) void*)&lds4[buf][w * 256 + i * 64],
                16, 0, 0);
        }
    };

    STAGE(0, 0);
    __syncthreads();   // drains vmcnt(0): buf0 ready

    for (int ct = 0; ct < 4; ++ct) {
        if (ct < 3) STAGE((ct + 1) & 1, ct + 1);   // prefetch next tile
        const short8* buf = (const short8*)lds4[ct & 1];
        #pragma unroll
        for (int sub = 0; sub < 2; ++sub) {
            const int brow = sub * 16 + l15;
            f32x4 acc0 = {0.f, 0.f, 0.f, 0.f}, acc1 = {0.f, 0.f, 0.f, 0.f};
            #pragma unroll
            for (int kk = 0; kk < 8; ++kk) {
                short8 b = buf[brow * 32 + ((kk * 4 + lhi) ^ (brow & 7))];
                acc0 = __builtin_amdgcn_mfma_f32_16x16x32_bf16(a0[kk], b, acc0, 0, 0, 0);
                acc1 = __builtin_amdgcn_mfma_f32_16x16x32_bf16(a1[kk], b, acc1, 0, 0, 0);
            }
            float cs = 0.f;
            #pragma unroll
            for (int g = 0; g < 4; ++g) {
                float e0 = EXP2F(acc0[g]);
                float e1 = EXP2F(acc1[g]);
                sume0[g] += e0;
                sume1[g] += e1;
                cs += e0 + e1;
            }
            if (offdiag) {
                cs += __shfl_xor(cs, 16, 64);
                cs += __shfl_xor(cs, 32, 64);
                if (lhi == 0) atomicAdd(&csum[ct * 32 + sub * 16 + l15], cs);
            }
        }
        __syncthreads();   // readers done + prefetch drained
    }

    // row sums: reduce across the 16 lanes of each row group, then atomicAdd
    #pragma unroll
    for (int g = 0; g < 4; ++g) {
        float v0 = sume0[g], v1 = sume1[g];
        v0 += __shfl_xor(v0, 1, 64); v0 += __shfl_xor(v0, 2, 64);
        v0 += __shfl_xor(v0, 4, 64); v0 += __shfl_xor(v0, 8, 64);
        v1 += __shfl_xor(v1, 1, 64); v1 += __shfl_xor(v1, 2, 64);
        v1 += __shfl_xor(v1, 4, 64); v1 += __shfl_xor(v1, 8, 64);
        if (l15 == 0) {
            atomicAdd(&psum[rowbase + lhi * 4 + g],      v0);
            atomicAdd(&psum[rowbase + 16 + lhi * 4 + g], v1);
        }
    }
    // column sums (csum finalized at the loop's last barrier)
    if (offdiag && tid < TILE) atomicAdd(&psum[colbase + tid], csum[tid]);
}

// Kernel 3: per-row: val = ln(psum[r] - exp(s_rr)) - pos_r; mean via atomicAdd.
// 16 lanes per row; dots recomputed in fp32 from the same bf16 buffers MFMA used.
__global__ __launch_bounds__(256) void reduce1(const ushort* __restrict__ zn,
                                               const ushort* __restrict__ zns,
                                               const float* __restrict__ psum,
                                               float* __restrict__ out) {
    int r = blockIdx.x * 16 + (threadIdx.x >> 4);
    int l = threadIdx.x & 15;
    const ushort* zr = zn  + (size_t)r * DD + l * 16;
    const ushort* sr = zns + (size_t)r * DD + l * 16;
    const ushort* pr = zn  + (size_t)(r ^ BB) * DD + l * 16;
    short8 z0 = *(const short8*)zr, z1 = *(const short8*)(zr + 8);
    short8 s0 = *(const short8*)sr, s1 = *(const short8*)(sr + 8);
    short8 p0 = *(const short8*)pr, p1 = *(const short8*)(pr + 8);
    float ds = 0.f, dp = 0.f;
    #pragma unroll
    for (int k = 0; k < 8; ++k) {
        float za = bf2f(z0[k]), zb = bf2f(z1[k]);
        ds += bf2f(s0[k]) * za + bf2f(s1[k]) * zb;   // zns . zn  (= KSCALE*dot_self)
        dp += bf2f(p0[k]) * za + bf2f(p1[k]) * zb;   // zn . zn_pos
    }
    #pragma unroll
    for (int m = 8; m; m >>= 1) {
        ds += __shfl_xor(ds, m, 64);
        dp += __shfl_xor(dp, m, 64);
    }
    if (l == 0) {
        float val = logf(psum[r] - EXP2F(ds)) - 2.0f * dp;
        atomicAdd(out, val * (1.0f / NN));
    }
}

extern "C" void kernel_launch(void* const* d_in, const int* in_sizes, int n_in,
                              void* d_out, int out_size, void* d_ws, size_t ws_size,
                              hipStream_t stream) {
    const float* zi = (const float*)d_in[0];
    const float* zj = (const float*)d_in[1];
    float* out = (float*)d_out;

    char* ws = (char*)d_ws;
    ushort* zn   = (ushort*)ws;                         // 4 MB
    ushort* zns  = (ushort*)(ws + (size_t)NN * DD * 2); // 4 MB
    float*  psum = (float*)(ws + (size_t)NN * DD * 4);  // 32 KB

    hipMemsetAsync(psum, 0, (size_t)NN * 4, stream);
    hipMemsetAsync(out, 0, sizeof(float), stream);
    norm_kernel<<<NN / 4, 256, 0, stream>>>(zi, zj, zn, zns);
    sim_kernel<<<NBLK, 256, 0, stream>>>(zn, zns, psum);
    reduce1<<<NN / 16, 256, 0, stream>>>(zn, zns, psum, out);
}

// Round 5
// 125.167 us; speedup vs baseline: 1.1064x; 1.1064x over previous
//
#include <hip/hip_runtime.h>
#include <hip/hip_bf16.h>

#define NN 8192
#define BB 4096
#define DD 256
#define TILE 128
#define NT 64                        // NN / TILE
#define NBLK 2080                    // NT*(NT+1)/2 triangular tiles
#define KSCALE 2.8853900817779268f   // 2 * log2(e): exp(sim) = exp2(KSCALE * dot)

typedef __attribute__((ext_vector_type(8))) short short8;
typedef __attribute__((ext_vector_type(4))) float f32x4;

static __device__ __forceinline__ float exp2_fast(float x) {
    float r; asm("v_exp_f32 %0, %1" : "=v"(r) : "v"(x)); return r;
}
static __device__ __forceinline__ ushort f2bf(float x) {
    __hip_bfloat16 h = __float2bfloat16(x);
    return *reinterpret_cast<ushort*>(&h);
}
static __device__ __forceinline__ float bf2f(short u) {
    unsigned int x = (unsigned int)(ushort)u << 16;
    float f; __builtin_memcpy(&f, &x, 4); return f;
}

// Kernel 1: L2-normalize rows of concat(z_i,z_j) -> zn (bf16) and zns = KSCALE*zn (bf16).
// Also zeroes the output scalar (block 0) so no memset dispatch is needed.
__global__ __launch_bounds__(256) void norm_kernel(const float* __restrict__ zi,
                                                   const float* __restrict__ zj,
                                                   ushort* __restrict__ zn,
                                                   ushort* __restrict__ zns,
                                                   float* __restrict__ out) {
    if (blockIdx.x == 0 && threadIdx.x == 0) out[0] = 0.f;
    int row  = (blockIdx.x * 256 + threadIdx.x) >> 6;
    int lane = threadIdx.x & 63;
    const float* src = (row < BB) ? (zi + (size_t)row * DD)
                                  : (zj + (size_t)(row - BB) * DD);
    float4 v = ((const float4*)src)[lane];
    float ss = v.x * v.x + v.y * v.y + v.z * v.z + v.w * v.w;
    #pragma unroll
    for (int m = 32; m; m >>= 1) ss += __shfl_xor(ss, m, 64);
    float inv = 1.0f / fmaxf(sqrtf(ss), 1e-8f);
    ushort4 o, os;
    o.x  = f2bf(v.x * inv);            o.y  = f2bf(v.y * inv);
    o.z  = f2bf(v.z * inv);            o.w  = f2bf(v.w * inv);
    float invs = inv * KSCALE;
    os.x = f2bf(v.x * invs);           os.y = f2bf(v.y * invs);
    os.z = f2bf(v.z * invs);           os.w = f2bf(v.w * invs);
    ((ushort4*)(zn  + (size_t)row * DD))[lane] = o;
    ((ushort4*)(zns + (size_t)row * DD))[lane] = os;
}

// Kernel 2: triangular 128x128 tile (bi<=bj), 2 waves x 64 rows.
// A (scaled, 128 VGPR) resident; B: 4 col-tiles fully prefetched via
// global_load_lds with counted-vmcnt waits (no barrier drain).
// Row-sums -> psum2D[bj][rows]; col-sums -> psum2D[bi][cols] (offdiag only).
// Disjoint-write scheme: every psum2D entry written exactly once, NO atomics.
__global__ __launch_bounds__(128, 2) void sim_kernel(const ushort* __restrict__ zn,
                                                     const ushort* __restrict__ zns,
                                                     float* __restrict__ psum) {
    __shared__ int4  lds4[4][1024];    // 4 col-tiles x (32 rows x 32 granules x 16B) = 64 KB
    __shared__ float csumW[2][TILE];   // per-wave column partials

    const int tid  = threadIdx.x;
    const int w    = tid >> 6;
    const int lane = tid & 63;
    const int l15  = lane & 15;
    const int lhi  = lane >> 4;

    // XCD-aware swizzle (2080 = 8*260, bijective) then triangular decode
    int bid = blockIdx.x;
    int idx = (bid & 7) * (NBLK / 8) + (bid >> 3);
    int bj  = (int)((sqrtf(8.0f * (float)idx + 1.0f) - 1.0f) * 0.5f);
    while ((bj + 1) * (bj + 2) / 2 <= idx) ++bj;
    while (bj * (bj + 1) / 2 > idx) --bj;
    int bi = idx - bj * (bj + 1) / 2;

    const int  rowbase = bi * TILE + w * 64;   // this wave's 64 rows
    const int  colbase = bj * TILE;
    const bool offdiag = (bi != bj);

    // --- A fragments first (so stage-load vmcnt counting below is exact) ---
    short8 a[4][8];
    #pragma unroll
    for (int rt = 0; rt < 4; ++rt)
        #pragma unroll
        for (int kk = 0; kk < 8; ++kk)
            a[rt][kk] = *(const short8*)(zns + (size_t)(rowbase + rt * 16 + l15) * DD
                                             + kk * 32 + lhi * 8);

    // --- issue ALL 4 stage tiles (8 gload_lds/thread each; 16B width) ---
    #pragma unroll
    for (int ct = 0; ct < 4; ++ct)
        #pragma unroll
        for (int i = 0; i < 8; ++i) {
            int d = i * 128 + tid;          // dest granule 0..1023
            int r = d >> 5, c = d & 31;     // staged row, granule-in-row
            const ushort* src = zn + (size_t)(colbase + ct * 32 + r) * DD
                                   + (size_t)((c ^ (r & 7)) * 8);
            __builtin_amdgcn_global_load_lds(
                (__attribute__((address_space(1))) void*)src,
                (__attribute__((address_space(3))) void*)&lds4[ct][i * 128 + w * 64],
                16, 0, 0);
        }
    __builtin_amdgcn_sched_barrier(0);   // wall: no stage-issue sinks past the waits

    f32x4 sume[4];
    #pragma unroll
    for (int rt = 0; rt < 4; ++rt) sume[rt] = (f32x4){0.f, 0.f, 0.f, 0.f};

    #pragma unroll
    for (int ct = 0; ct < 4; ++ct) {
        // counted vmcnt: stage-loads issued after tile ct = 8*(3-ct)
        if      (ct == 0) asm volatile("s_waitcnt vmcnt(24)" ::: "memory");
        else if (ct == 1) asm volatile("s_waitcnt vmcnt(16)" ::: "memory");
        else if (ct == 2) asm volatile("s_waitcnt vmcnt(8)"  ::: "memory");
        else              asm volatile("s_waitcnt vmcnt(0)"  ::: "memory");
        __builtin_amdgcn_s_barrier();
        __builtin_amdgcn_sched_barrier(0);

        const short8* buf = (const short8*)lds4[ct];
        #pragma unroll
        for (int sub = 0; sub < 2; ++sub) {
            const int brow = sub * 16 + l15;
            short8 b[8];
            #pragma unroll
            for (int kk = 0; kk < 8; ++kk)
                b[kk] = buf[brow * 32 + ((kk * 4 + lhi) ^ (brow & 7))];
            f32x4 acc[4];
            #pragma unroll
            for (int rt = 0; rt < 4; ++rt) acc[rt] = (f32x4){0.f, 0.f, 0.f, 0.f};
            #pragma unroll
            for (int kk = 0; kk < 8; ++kk)
                #pragma unroll
                for (int rt = 0; rt < 4; ++rt)
                    acc[rt] = __builtin_amdgcn_mfma_f32_16x16x32_bf16(a[rt][kk], b[kk], acc[rt], 0, 0, 0);
            float cs = 0.f;
            #pragma unroll
            for (int rt = 0; rt < 4; ++rt)
                #pragma unroll
                for (int g = 0; g < 4; ++g) {
                    float e = exp2_fast(acc[rt][g]);
                    sume[rt][g] += e;
                    cs += e;
                }
            if (offdiag) {   // block-uniform branch
                cs += __shfl_xor(cs, 16, 64);
                cs += __shfl_xor(cs, 32, 64);
                if (lhi == 0) csumW[w][ct * 32 + sub * 16 + l15] = cs;
            }
        }
    }

    // row sums: reduce over the 16 col-lanes, one plain store per row
    #pragma unroll
    for (int rt = 0; rt < 4; ++rt)
        #pragma unroll
        for (int g = 0; g < 4; ++g) {
            float v = sume[rt][g];
            v += __shfl_xor(v, 1, 64); v += __shfl_xor(v, 2, 64);
            v += __shfl_xor(v, 4, 64); v += __shfl_xor(v, 8, 64);
            if (l15 == 0)
                psum[(size_t)bj * NN + rowbase + rt * 16 + lhi * 4 + g] = v;
        }
    // col sums: combine the 2 waves' partials, one plain store per col
    if (offdiag) {
        __syncthreads();
        if (tid < TILE)
            psum[(size_t)bi * NN + colbase + tid] = csumW[0][tid] + csumW[1][tid];
    }
}

// Kernel 3: per row r: val = ln(Sum_s psum[s][r] - exp(s_rr)) - pos_r.
// 16 lanes/row, 64 rows/block (1024 thr), one atomicAdd per block (128 total).
__global__ __launch_bounds__(1024) void reduce_kernel(const ushort* __restrict__ zn,
                                                      const ushort* __restrict__ zns,
                                                      const float* __restrict__ psum,
                                                      float* __restrict__ out) {
    const int tid  = threadIdx.x;
    const int rloc = tid >> 4;                 // 0..63
    const int r    = blockIdx.x * 64 + rloc;
    const int l    = tid & 15;

    float S = 0.f;
    #pragma unroll
    for (int i = 0; i < 4; ++i) S += psum[(size_t)(i * 16 + l) * NN + r];

    const ushort* zr = zn  + (size_t)r * DD + l * 16;
    const ushort* sr = zns + (size_t)r * DD + l * 16;
    const ushort* pr = zn  + (size_t)(r ^ BB) * DD + l * 16;
    short8 z0 = *(const short8*)zr, z1 = *(const short8*)(zr + 8);
    short8 s0 = *(const short8*)sr, s1 = *(const short8*)(sr + 8);
    short8 p0 = *(const short8*)pr, p1 = *(const short8*)(pr + 8);
    float ds = 0.f, dp = 0.f;
    #pragma unroll
    for (int k = 0; k < 8; ++k) {
        float za = bf2f(z0[k]), zb = bf2f(z1[k]);
        ds += bf2f(s0[k]) * za + bf2f(s1[k]) * zb;   // KSCALE * self-dot
        dp += bf2f(p0[k]) * za + bf2f(p1[k]) * zb;   // dot with positive pair
    }
    #pragma unroll
    for (int m = 1; m < 16; m <<= 1) {
        S  += __shfl_xor(S,  m, 64);
        ds += __shfl_xor(ds, m, 64);
        dp += __shfl_xor(dp, m, 64);
    }
    __shared__ float red[64];
    if (l == 0) red[rloc] = logf(S - exp2_fast(ds)) - 2.0f * dp;
    __syncthreads();
    if (tid < 64) {
        float v = red[tid];
        #pragma unroll
        for (int m = 32; m; m >>= 1) v += __shfl_xor(v, m, 64);
        if (tid == 0) atomicAdd(out, v * (1.0f / NN));
    }
}

extern "C" void kernel_launch(void* const* d_in, const int* in_sizes, int n_in,
                              void* d_out, int out_size, void* d_ws, size_t ws_size,
                              hipStream_t stream) {
    const float* zi = (const float*)d_in[0];
    const float* zj = (const float*)d_in[1];
    float* out = (float*)d_out;

    char* ws = (char*)d_ws;
    ushort* zn   = (ushort*)ws;                          // 4 MB
    ushort* zns  = (ushort*)(ws + (size_t)NN * DD * 2);  // 4 MB
    float*  psum = (float*)(ws + (size_t)NN * DD * 4);   // 64*8192*4 = 2 MB

    norm_kernel<<<NN / 4, 256, 0, stream>>>(zi, zj, zn, zns, out);
    sim_kernel<<<NBLK, 128, 0, stream>>>(zn, zns, psum);
    reduce_kernel<<<NN / 64, 1024, 0, stream>>>(zn, zns, psum, out);
}